// Round 7
// baseline (1923.048 us; speedup 1.0000x reference)
//
#include <hip/hip_runtime.h>

// LSTM_73512660239038: 64-step LSTM, H=B=1024, INPUT_DIM=1.
// R7: A-operand (W) no longer staged through LDS — loaded global->VGPR
// directly (fragment = 8 contiguous f16/lane), register-double-buffered one
// K-tile ahead. LDS now stages only h (B operand): per-iter LDS traffic
// 128KB -> 80KB. fp16 single-pass numerics (R6), fp32 accum.

typedef _Float16 f16;
typedef __attribute__((ext_vector_type(8))) _Float16 f16x8;
typedef __attribute__((ext_vector_type(4))) float f32x4;

typedef const __attribute__((address_space(1))) unsigned char* gbl_ptr_t;
typedef __attribute__((address_space(3))) unsigned char* lds_ptr_t;

__device__ __forceinline__ float fsig(float z) {
  return 1.0f / (1.0f + __expf(-z));
}
__device__ __forceinline__ float ftanh(float z) {
  float a = fabsf(z);
  float e = __expf(-2.0f * a);
  float t = (1.0f - e) / (1.0f + e);
  return z < 0.0f ? -t : t;
}

// ---------------- prep: cast weights to fp16 (RNE) ----------------
__global__ __launch_bounds__(256) void k_prep(
    const float* __restrict__ wg, const float* __restrict__ wi,
    const float* __restrict__ wf, const float* __restrict__ wo,
    const float* __restrict__ wp,
    f16* __restrict__ Wf, float* __restrict__ w0,
    f16* __restrict__ WPf) {
  const int NW = 4 * 1024 * 1025;
  const int NP = 1024 * 1024;
  int i = blockIdx.x * blockDim.x + threadIdx.x;
  const int stride = gridDim.x * blockDim.x;
  for (; i < NW + NP; i += stride) {
    if (i < NW) {
      const int gate = i / (1024 * 1025);
      const int rem = i - gate * (1024 * 1025);
      const int r = rem / 1025;
      const int k = rem - r * 1025;
      const float* w = gate == 0 ? wg : gate == 1 ? wi : gate == 2 ? wf : wo;
      const float v = w[rem];
      if (k == 0) {
        w0[gate * 1024 + r] = v;            // x-weight column, kept fp32
      } else {
        Wf[(gate * 1024 + r) * 1024 + (k - 1)] = (f16)v;
      }
    } else {
      WPf[i - NW] = (f16)wp[i - NW];
    }
  }
}

// ---------------- per-step fused kernel (R7: A direct-to-VGPR) ----------------
// grid 256: hrtile = bx&31 (32 h-rows), btile = bx>>5 (128 batch cols).
// 8 waves: gate = wid>>1 (A rows gate*32..+32), wn = wid&1 (B cols wn*64..+64).
// BK=64. LDS 64KB: 2 h-staging bufs (16KB each) in [0,32KB); z-exchange
// reuses [0,64KB) after the K-loop. A (W) fragments: global->VGPR, ping-pong.
__global__ __launch_bounds__(512) void k_step(
    const f16* __restrict__ Wf,
    const float* __restrict__ w0,
    const float* __restrict__ x,
    const float* __restrict__ bg, const float* __restrict__ bi,
    const float* __restrict__ bff, const float* __restrict__ bo,
    const f16* __restrict__ Hin, f16* __restrict__ Hout,
    float* __restrict__ c, int t) {
  __shared__ alignas(16) unsigned char smem[65536];
  const int tid = threadIdx.x;
  const int wid = tid >> 6;
  const int lane = tid & 63;
  const int gate = wid >> 1;                // A-row group AND output gate
  const int wn = wid & 1;                   // B-col half
  const int hr0 = (blockIdx.x & 31) * 32;
  const int b0 = (blockIdx.x >> 5) * 128;

  // ---- B (h) staging addresses: 1024 chunks of 16B per 16KB tile ----
  long boffb[2];
  int ldso[2];
#pragma unroll
  for (int s = 0; s < 2; ++s) {
    const int ch = s * 512 + tid;
    const int row = ch >> 3;
    const int sl = ch & 7;
    const int sg = sl ^ (row & 7);          // swizzle on the GLOBAL source
    boffb[s] = ((long)(b0 + row) << 10) + sg * 8;
    ldso[s] = ch * 16;
  }

  // ---- A (W) fragment element-offsets (without kt term) ----
  // frag (m, ks): row = gate*1024 + hr0 + m*16 + (lane&15); k = ks*32 + (lane>>4)*8
  int aoff[2][2];
#pragma unroll
  for (int m = 0; m < 2; ++m)
#pragma unroll
    for (int ks = 0; ks < 2; ++ks)
      aoff[m][ks] = (gate * 1024 + hr0 + m * 16 + (lane & 15)) * 1024 +
                    ks * 32 + (lane >> 4) * 8;

  f32x4 acc[2][4];
#pragma unroll
  for (int m = 0; m < 2; ++m)
#pragma unroll
    for (int n = 0; n < 4; ++n) acc[m][n] = (f32x4){0.f, 0.f, 0.f, 0.f};

  f16x8 Abuf[2][2][2];                      // [kt&1][m][ks], all static indices

  // prologue: stage h buf0, load A(kt=0)
#pragma unroll
  for (int s = 0; s < 2; ++s)
    __builtin_amdgcn_global_load_lds((gbl_ptr_t)(const void*)(Hin + boffb[s]),
                                     (lds_ptr_t)(void*)(smem + ldso[s]), 16, 0, 0);
#pragma unroll
  for (int m = 0; m < 2; ++m)
#pragma unroll
    for (int ks = 0; ks < 2; ++ks)
      Abuf[0][m][ks] = *(const f16x8*)(Wf + aoff[m][ks]);
  __syncthreads();

#pragma unroll
  for (int kt = 0; kt < 16; ++kt) {
    const unsigned pb = (kt & 1) * 16384;
    // ---- stage h(kt+1) and prefetch A(kt+1) (issued BEFORE compute) ----
    if (kt < 15) {
      const unsigned nb = ((kt + 1) & 1) * 16384;
      const int k0 = (kt + 1) << 6;
#pragma unroll
      for (int s = 0; s < 2; ++s)
        __builtin_amdgcn_global_load_lds((gbl_ptr_t)(const void*)(Hin + boffb[s] + k0),
                                         (lds_ptr_t)(void*)(smem + nb + ldso[s]), 16, 0, 0);
#pragma unroll
      for (int m = 0; m < 2; ++m)
#pragma unroll
        for (int ks = 0; ks < 2; ++ks)
          Abuf[(kt + 1) & 1][m][ks] = *(const f16x8*)(Wf + aoff[m][ks] + k0);
    }
    // ---- compute: wave tile 32 (A rows) x 64 (B cols), A from VGPR ----
    __builtin_amdgcn_s_setprio(1);
#pragma unroll
    for (int ks = 0; ks < 2; ++ks) {
      const int slot = (ks << 2) + (lane >> 4);
#pragma unroll
      for (int n = 0; n < 4; ++n) {
        const int trb = wn * 64 + n * 16 + (lane & 15);
        const int offb = trb * 128 + ((slot ^ (trb & 7)) << 4);
        const f16x8 bF = *(const f16x8*)(smem + pb + offb);
#pragma unroll
        for (int m = 0; m < 2; ++m) {
          acc[m][n] = __builtin_amdgcn_mfma_f32_16x16x32_f16(Abuf[kt & 1][m][ks], bF,
                                                             acc[m][n], 0, 0, 0);
        }
      }
    }
    __builtin_amdgcn_s_setprio(0);
    __syncthreads();   // h(kt+1) landed; buf kt safe to overwrite next iter
  }

  // ---- z exchange through LDS (swizzled r to dodge bank conflicts) ----
  float* zl = (float*)smem;                 // [4 gates][128 b][32 r] fp32 = 64KB
#pragma unroll
  for (int n = 0; n < 4; ++n) {
    const int b = wn * 64 + n * 16 + (lane & 15);
#pragma unroll
    for (int m = 0; m < 2; ++m) {
#pragma unroll
      for (int j = 0; j < 4; ++j) {
        const int r = m * 16 + (lane >> 4) * 4 + j;
        const int rs = (r ^ ((b & 7) << 2)) ^ ((b >> 3) & 1);
        zl[gate * 4096 + b * 32 + rs] = acc[m][n][j];
      }
    }
  }
  __syncthreads();
  // ---- elementwise gates; bias indexed by BATCH column (ref quirk) ----
  for (int q = 0; q < 8; ++q) {
    const int idx = q * 512 + tid;
    const int r = idx & 31, bb = idx >> 5;
    const int rs = (r ^ ((bb & 7) << 2)) ^ ((bb >> 3) & 1);
    const int gb = b0 + bb;
    const int gr = hr0 + r;
    float zg = zl[bb * 32 + rs];
    float zi = zl[4096 + bb * 32 + rs];
    float zf = zl[8192 + bb * 32 + rs];
    float zo = zl[12288 + bb * 32 + rs];
    const float xv = x[gb * 64 + t];
    zg += w0[gr] * xv + bg[gb];
    zi += w0[1024 + gr] * xv + bi[gb];
    zf += w0[2048 + gr] * xv + bff[gb];
    zo += w0[3072 + gr] * xv + bo[gb];
    const float g = ftanh(zg), ii = fsig(zi), ff = fsig(zf), oo = fsig(zo);
    const long ci = (long)gb * 1024 + gr;   // c and h stored [B][H]
    const float c2 = g * ii + c[ci] * ff;
    c[ci] = c2;
    const float h2 = ftanh(c2) * oo;
    Hout[ci] = (f16)h2;
  }
}

// ---------------- final projection: out[b][r] = hs[b,:]·wp[r,:] + bp[r] ----------------
// single-pass fp16.
__global__ __launch_bounds__(256) void k_proj(
    const f16* __restrict__ H, const f16* __restrict__ WPf,
    const float* __restrict__ bp, float* __restrict__ out) {
  __shared__ alignas(16) unsigned char smem[32768];
  const int tid = threadIdx.x;
  const int wid = tid >> 6;
  const int lane = tid & 63;
  const int b0 = (blockIdx.x >> 3) * 128;   // M = batch
  const int r0 = (blockIdx.x & 7) * 128;    // N = output row

  f32x4 acc[2][8];
#pragma unroll
  for (int m = 0; m < 2; ++m)
#pragma unroll
    for (int n = 0; n < 8; ++n) acc[m][n] = (f32x4){0.f, 0.f, 0.f, 0.f};

  for (int kt = 0; kt < 16; ++kt) {
    const int k0 = kt << 6;
    __syncthreads();
#pragma unroll
    for (int j = 0; j < 4; ++j) {
      const int i = wid * 4 + j;
      const int ch = i * 64 + lane;
      const int row = ch >> 3;
      const int sl = ch & 7;
      const int sg = sl ^ (row & 7);
      const long aoff = ((long)(b0 + row) << 10) + k0 + sg * 8;
      const long boff = ((long)(r0 + row) << 10) + k0 + sg * 8;
      __builtin_amdgcn_global_load_lds((gbl_ptr_t)(const void*)(H + aoff),
                                       (lds_ptr_t)(void*)(smem + i * 1024), 16, 0, 0);
      __builtin_amdgcn_global_load_lds((gbl_ptr_t)(const void*)(WPf + boff),
                                       (lds_ptr_t)(void*)(smem + 16384 + i * 1024), 16, 0, 0);
    }
    __syncthreads();
#pragma unroll
    for (int ks = 0; ks < 2; ++ks) {
      const int slot = (ks << 2) + (lane >> 4);
      f16x8 aF[2];
#pragma unroll
      for (int m = 0; m < 2; ++m) {
        const int tr = wid * 32 + m * 16 + (lane & 15);
        const int off = tr * 128 + ((slot ^ (tr & 7)) << 4);
        aF[m] = *(const f16x8*)(smem + off);
      }
#pragma unroll
      for (int n = 0; n < 8; ++n) {
        const int tr = n * 16 + (lane & 15);
        const int off = tr * 128 + ((slot ^ (tr & 7)) << 4);
        const f16x8 bF = *(const f16x8*)(smem + 16384 + off);
#pragma unroll
        for (int m = 0; m < 2; ++m) {
          acc[m][n] = __builtin_amdgcn_mfma_f32_16x16x32_f16(aF[m], bF, acc[m][n], 0, 0, 0);
        }
      }
    }
  }
#pragma unroll
  for (int n = 0; n < 8; ++n) {
    const int rr = r0 + n * 16 + (lane & 15);
    const float bpv = bp[rr];
#pragma unroll
    for (int m = 0; m < 2; ++m) {
#pragma unroll
      for (int j = 0; j < 4; ++j) {
        const int bbb = b0 + wid * 32 + m * 16 + (lane >> 4) * 4 + j;
        out[(long)bbb * 1024 + rr] = acc[m][n][j] + bpv;
      }
    }
  }
}

extern "C" void kernel_launch(void* const* d_in, const int* in_sizes, int n_in,
                              void* d_out, int out_size, void* d_ws, size_t ws_size,
                              hipStream_t stream) {
  (void)in_sizes; (void)n_in; (void)out_size; (void)ws_size;
  const float* x  = (const float*)d_in[0];
  const float* wg = (const float*)d_in[1];
  const float* bg = (const float*)d_in[2];
  const float* wi = (const float*)d_in[3];
  const float* bi = (const float*)d_in[4];
  const float* wf = (const float*)d_in[5];
  const float* bf = (const float*)d_in[6];
  const float* wo = (const float*)d_in[7];
  const float* bo = (const float*)d_in[8];
  const float* wp = (const float*)d_in[9];
  const float* bp = (const float*)d_in[10];

  char* ws = (char*)d_ws;
  size_t off = 0;
  auto alloc = [&](size_t bytes) {
    char* p = ws + off;
    off += (bytes + 255) & ~(size_t)255;
    return p;
  };
  f16*   Wf  = (f16*)alloc(8388608);    // [4096][1024] fp16
  f16*   WPf = (f16*)alloc(2097152);    // [1024][1024] fp16
  float* w0  = (float*)alloc(16384);    // [4][1024] x-weight col fp32
  f16*   h0  = (f16*)alloc(2097152);    // h stored [B][H] fp16
  f16*   h1  = (f16*)alloc(2097152);
  float* c   = (float*)alloc(4194304);  // [B][H] fp32

  hipMemsetAsync(h0, 0, 2097152, stream);
  hipMemsetAsync(c, 0, 4194304, stream);

  k_prep<<<2048, 256, 0, stream>>>(wg, wi, wf, wo, wp, Wf, w0, WPf);

  for (int t = 0; t < 64; ++t) {
    const f16* ih = (t & 1) ? h1 : h0;
    f16* oh = (t & 1) ? h0 : h1;
    k_step<<<256, 512, 0, stream>>>(Wf, w0, x, bg, bi, bf, bo, ih, oh, c, t);
  }
  // after t=63 (odd) the freshest h lives in buffer 0
  k_proj<<<64, 256, 0, stream>>>(h0, WPf, bp, (float*)d_out);
}